// Round 6
// baseline (127.107 us; speedup 1.0000x reference)
//
#include <hip/hip_runtime.h>
#include <hip/hip_bf16.h>

// B=16, T=2048, C=384, H=64. out = softmax((x Wq)(x Wk)^T / sqrt(C)) (x Wv)
// ws (bf16): Qb[32768*64] | Kb[32768*64] | Vt[16][64][2048] | Wt[6*192*64]
// R9: flash K/V staging via global_load_lds DMA (width 16). LDS dest is
// LINEAR (wave-uniform base + lane*16, rule #21); the XOR swizzle is applied
// to the PER-LANE GLOBAL SOURCE address (m173 pattern): lane l covers row
// r = wv*16+i*8+(l>>3), source col byte = ((l&7)^(l>>3))<<4; reads keep the
// same XOR (tp). Removes 4 global->reg loads + 4 ds_writes + addressing per
// wave-iter; DMA drained by the existing end-of-iter barrier (K/V L2-hot).
// Plus s_setprio(1) around S and PV MFMA clusters (T5, m191: attn +4-7%).
// Keeps R8's single-barrier PV-lags-S pipeline + XOR-swizzled LDS.

typedef __bf16 bf16;
typedef __attribute__((ext_vector_type(8))) __bf16 bf16x8;
typedef __attribute__((ext_vector_type(4))) __bf16 bf16x4;
typedef __attribute__((ext_vector_type(4))) float f32x4;

#define SCALE_LOG2E (0.051031036307982884f * 1.4426950408889634f)

// swizzled element pointer into a [64][64] bf16 tile (128 B rows):
// byte = row*128 + (cbyte ^ ((row&7)<<4)); bijective, keeps 16B/8B alignment.
__device__ __forceinline__ bf16* tp(bf16* base, int row, int cbyte) {
    return (bf16*)((char*)base + row * 128 + (cbyte ^ ((row & 7) << 4)));
}

typedef __attribute__((address_space(3))) void lds_v;
typedef __attribute__((address_space(1))) const void glb_v;
__device__ __forceinline__ void dma16(const void* g, void* l) {
    __builtin_amdgcn_global_load_lds((glb_v*)g, (lds_v*)l, 16, 0, 0);
}

// ---------------------------------------------------------------------------
// Kernel 0: pack W^T, Wt[ck][h][c'] (c = ck*64+c', h in [0,192) = Wq|Wk|Wv).
// ---------------------------------------------------------------------------
__global__ void pack_w(const float* __restrict__ Wq, const float* __restrict__ Wk,
                       const float* __restrict__ Wv, bf16* __restrict__ Wt) {
    int idx = blockIdx.x * 256 + threadIdx.x;      // 0..73727
    int cc = idx & 63;
    int hh = (idx >> 6) % 192;
    int ck = idx / 12288;
    const float* W = (hh < 64) ? Wq : (hh < 128 ? Wk : Wv);
    Wt[idx] = (bf16)W[(ck * 64 + cc) * 64 + (hh & 63)];
}

// ---------------------------------------------------------------------------
// Kernel 1: QKV projection (unchanged from the 131 us baseline).
// ---------------------------------------------------------------------------
__global__ __launch_bounds__(256) void qkv_proj(const float* __restrict__ x,
                                                const bf16* __restrict__ Wt,
                                                bf16* __restrict__ Qb,
                                                bf16* __restrict__ Kb,
                                                bf16* __restrict__ Vtg) {
    __shared__ __align__(16) bf16 Xs[2][64 * 72];
    __shared__ __align__(16) bf16 Ws[2][192 * 72];

    const int tid = threadIdx.x;
    const int wv = tid >> 6, lane = tid & 63, quad = lane >> 4, l16 = lane & 15;
    const int row0 = blockIdx.x * 64;

    f32x4 acc[12];
#pragma unroll
    for (int n = 0; n < 12; n++) acc[n] = (f32x4){0.f, 0.f, 0.f, 0.f};

    float4 xpre[4];
    bf16x8 wpre[6];
#pragma unroll
    for (int k = 0; k < 4; k++) {
        int g = tid + k * 256;
        xpre[k] = *(const float4*)(x + (long)(row0 + (g >> 4)) * 384 + (g & 15) * 4);
    }
#pragma unroll
    for (int k = 0; k < 6; k++)
        wpre[k] = *(const bf16x8*)(Wt + (tid + k * 256) * 8);

    for (int ck = 0; ck < 6; ck++) {
        bf16* Xc = Xs[ck & 1];
        bf16* Wc = Ws[ck & 1];
#pragma unroll
        for (int k = 0; k < 4; k++) {
            int g = tid + k * 256;
            float4 xv = xpre[k];
            *(bf16x4*)(&Xc[(g >> 4) * 72 + (g & 15) * 4]) =
                (bf16x4){(bf16)xv.x, (bf16)xv.y, (bf16)xv.z, (bf16)xv.w};
        }
#pragma unroll
        for (int k = 0; k < 6; k++) {
            int g = tid + k * 256;
            *(bf16x8*)(&Wc[(g >> 3) * 72 + (g & 7) * 8]) = wpre[k];
        }
        if (ck < 5) {
#pragma unroll
            for (int k = 0; k < 4; k++) {
                int g = tid + k * 256;
                xpre[k] = *(const float4*)(x + (long)(row0 + (g >> 4)) * 384 +
                                           (ck + 1) * 64 + (g & 15) * 4);
            }
#pragma unroll
            for (int k = 0; k < 6; k++)
                wpre[k] = *(const bf16x8*)(Wt + (ck + 1) * 12288 + (tid + k * 256) * 8);
        }
        __syncthreads();
#pragma unroll
        for (int kh = 0; kh < 2; kh++) {
            bf16x8 a = *(bf16x8*)(&Xc[(wv * 16 + l16) * 72 + kh * 32 + quad * 8]);
#pragma unroll
            for (int n = 0; n < 12; n++) {
                bf16x8 b = *(bf16x8*)(&Wc[(n * 16 + l16) * 72 + kh * 32 + quad * 8]);
                acc[n] = __builtin_amdgcn_mfma_f32_16x16x32_bf16(a, b, acc[n], 0, 0, 0);
            }
        }
    }

    __syncthreads();
    const int drow = wv * 16 + quad * 4;
#pragma unroll
    for (int n = 0; n < 4; n++) {
#pragma unroll
        for (int r = 0; r < 4; r++) {
            Xs[0][(drow + r) * 72 + n * 16 + l16] = (bf16)(acc[n][r] * SCALE_LOG2E);
            Xs[1][(drow + r) * 72 + n * 16 + l16] = (bf16)acc[n + 4][r];
            Ws[0][(n * 16 + l16) * 72 + drow + r] = (bf16)acc[n + 8][r];
        }
    }
    __syncthreads();
    const int b = row0 >> 11, t0 = row0 & 2047;
    const int srow = tid >> 2, scb = (tid & 3) * 16;
#pragma unroll
    for (int i = 0; i < 2; i++) {
        *(bf16x8*)(Qb + (long)(row0 + srow) * 64 + scb + i * 8) =
            *(bf16x8*)(&Xs[0][srow * 72 + scb + i * 8]);
        *(bf16x8*)(Kb + (long)(row0 + srow) * 64 + scb + i * 8) =
            *(bf16x8*)(&Xs[1][srow * 72 + scb + i * 8]);
        *(bf16x8*)(Vtg + (long)(b * 64 + srow) * 2048 + t0 + scb + i * 8) =
            *(bf16x8*)(&Ws[0][srow * 72 + scb + i * 8]);
    }
}

// ---------------------------------------------------------------------------
// Kernel 2: flash attention, 512 blocks x 256 thr (4 waves), 32 k-iters.
// Single barrier/iter (PV lags S by 1). Tiles [64][64] bf16, 128 B rows,
// XOR-swizzled. K/V staged by global_load_lds DMA (linear LDS dest,
// inverse-swizzled per-lane global source). LDS 49152 B:
//   Qs/Ps0 @0 | KsA 2x8192 @8192 | VsA 2x8192 @24576 | Ps1 @40960
//   Om [64][68] f32 overlays @8192 (epilogue only).
// Parity audit: DMA K[kt+1] -> buf[(kt+1)&1], S reads buf[kt&1] (opposite);
// DMA V[kt] -> buf[kt&1], PV reads buf[(kt+1)&1] = V[kt-1] (opposite);
// Ps write [kt&1], PV reads [(kt-1)&1] (opposite). End-of-iter barrier's
// vmcnt(0) drain publishes the DMA tiles.
// ---------------------------------------------------------------------------
__global__ __launch_bounds__(256) void flash_attn(const bf16* __restrict__ Qb,
                                                  const bf16* __restrict__ Kb,
                                                  const bf16* __restrict__ Vtg,
                                                  float* __restrict__ out) {
    __shared__ __align__(16) char smem[49152];
    bf16* Qs  = (bf16*)smem;                  // [64][64]; Ps0 overlays after hoist
    bf16* Ps0 = Qs;
    bf16* Ps1 = (bf16*)(smem + 40960);

    const int tid = threadIdx.x;
    const int wv = tid >> 6, lane = tid & 63, quad = lane >> 4, l16 = lane & 15;
    // XCD-aware swizzle: keep a batch's K/V resident in one XCD's L2.
    const int i0 = blockIdx.x;
    const int b = (i0 & 7) + 8 * ((i0 >> 3) >> 5);
    const int qt = (i0 >> 3) & 31;

    const bf16* Qg = Qb + (long)(b * 2048 + qt * 64) * 64;
    const char* KgB = (const char*)(Kb + (long)b * 2048 * 64);
    const char* VgB = (const char*)(Vtg + (long)b * 64 * 2048);

    const int srow = tid >> 2, scb = (tid & 3) * 16;
    // stage Q tile [64][64] (swizzled, regular stores)
    *(bf16x8*)tp(Qs, srow, scb * 2)      = *(const bf16x8*)(Qg + srow * 64 + scb);
    *(bf16x8*)tp(Qs, srow, scb * 2 + 16) = *(const bf16x8*)(Qg + srow * 64 + scb + 8);

    // DMA staging geometry: wave wv, call i covers LDS bytes
    // [wv*2048 + i*1024, +1024) of a tile; lane l -> row rl0+i*8, source col
    // byte srcc = ((l&7)^(l>>3))<<4 (inverse of the tp XOR, constant/lane).
    const int rl0  = wv * 16 + (lane >> 3);
    const int srcc = (((lane & 7) ^ (lane >> 3)) << 4);

    // stage K[0] via DMA into parity-0 buffer
#pragma unroll
    for (int i = 0; i < 2; i++)
        dma16(KgB + (long)(rl0 + i * 8) * 128 + srcc,
              smem + 8192 + wv * 2048 + i * 1024);

    f32x4 o[4], ol;
#pragma unroll
    for (int n = 0; n < 4; n++) o[n] = (f32x4){0.f, 0.f, 0.f, 0.f};
    ol = (f32x4){0.f, 0.f, 0.f, 0.f};

    __syncthreads();            // drains Q stores + K[0] DMA (vmcnt+lgkm)
    // hoist Q^T b-frags (loop-invariant)
    bf16x8 qb[4][2];
#pragma unroll
    for (int nt = 0; nt < 4; nt++)
#pragma unroll
        for (int kh = 0; kh < 2; kh++)
            qb[nt][kh] = *(bf16x8*)tp(Qs, nt * 16 + l16, kh * 64 + quad * 16);
    __syncthreads();            // all waves hoisted before Ps0 (=Qs) writes

    const bf16 one = (bf16)1.0f;
    const bf16x8 ones = {one, one, one, one, one, one, one, one};

#pragma unroll 2
    for (int kt = 0; kt < 32; kt++) {
        bf16* Kc  = (bf16*)(smem + 8192  + (kt & 1) * 8192);       // S src: K[kt]
        char* KnB = smem + 8192  + ((kt + 1) & 1) * 8192;          // DMA K[kt+1]
        char* VnB = smem + 24576 + (kt & 1) * 8192;                // DMA V[kt]
        bf16* Vp  = (bf16*)(smem + 24576 + ((kt + 1) & 1) * 8192); // PV src: V[kt-1]
        bf16* Pw = (kt & 1) ? Ps1 : Ps0;                           // write Ps[kt]
        bf16* Pr = (kt & 1) ? Ps0 : Ps1;                           // read  Ps[kt-1]

        // issue DMA staging (async; published by this iter's end barrier)
        if (kt < 31) {
#pragma unroll
            for (int i = 0; i < 2; i++)
                dma16(KgB + (long)((kt + 1) * 64 + rl0 + i * 8) * 128 + srcc,
                      KnB + wv * 2048 + i * 1024);
        }
#pragma unroll
        for (int i = 0; i < 2; i++)
            dma16(VgB + (long)(rl0 + i * 8) * 4096 + (long)kt * 128 + srcc,
                  VnB + wv * 2048 + i * 1024);

        // S^T[kt] = K Q^T : wave's key subtile (m=wv), all 4 q-tiles
        f32x4 s[4];
#pragma unroll
        for (int nt = 0; nt < 4; nt++) s[nt] = (f32x4){0.f, 0.f, 0.f, 0.f};
        __builtin_amdgcn_s_setprio(1);
#pragma unroll
        for (int kh = 0; kh < 2; kh++) {
            bf16x8 ka = *(bf16x8*)tp(Kc, wv * 16 + l16, kh * 64 + quad * 16);
#pragma unroll
            for (int nt = 0; nt < 4; nt++)
                s[nt] = __builtin_amdgcn_mfma_f32_16x16x32_bf16(ka, qb[nt][kh], s[nt], 0, 0, 0);
        }
        __builtin_amdgcn_s_setprio(0);
        // p = exp2(s), pack 4 -> b64 store into Ps[kt]
#pragma unroll
        for (int nt = 0; nt < 4; nt++) {
            bf16x4 pp;
#pragma unroll
            for (int r = 0; r < 4; r++)
                pp[r] = (bf16)__builtin_amdgcn_exp2f(s[nt][r]);
            *(bf16x4*)tp(Pw, nt * 16 + l16, wv * 32 + quad * 8) = pp;
        }

        // O^T += V[kt-1]^T Ps[kt-1] : wave's q subtile (n=wv), 4 h-tiles + l
        if (kt) {
            __builtin_amdgcn_s_setprio(1);
#pragma unroll
            for (int kh = 0; kh < 2; kh++) {
                bf16x8 pb = *(bf16x8*)tp(Pr, wv * 16 + l16, kh * 64 + quad * 16);
#pragma unroll
                for (int mt = 0; mt < 4; mt++) {
                    bf16x8 va = *(bf16x8*)tp(Vp, mt * 16 + l16, kh * 64 + quad * 16);
                    o[mt] = __builtin_amdgcn_mfma_f32_16x16x32_bf16(va, pb, o[mt], 0, 0, 0);
                }
                ol = __builtin_amdgcn_mfma_f32_16x16x32_bf16(ones, pb, ol, 0, 0, 0);
            }
            __builtin_amdgcn_s_setprio(0);
        }
        __syncthreads();        // publishes DMA K[kt+1],V[kt] and Ps[kt]
    }

    // peeled PV[31]: Ps[31] in Ps1, V[31] in VsA parity 1
    {
        bf16* Pr = Ps1;
        bf16* Vp = (bf16*)(smem + 24576 + 8192);
#pragma unroll
        for (int kh = 0; kh < 2; kh++) {
            bf16x8 pb = *(bf16x8*)tp(Pr, wv * 16 + l16, kh * 64 + quad * 16);
#pragma unroll
            for (int mt = 0; mt < 4; mt++) {
                bf16x8 va = *(bf16x8*)tp(Vp, mt * 16 + l16, kh * 64 + quad * 16);
                o[mt] = __builtin_amdgcn_mfma_f32_16x16x32_bf16(va, pb, o[mt], 0, 0, 0);
            }
            ol = __builtin_amdgcn_mfma_f32_16x16x32_bf16(ones, pb, ol, 0, 0, 0);
        }
    }

    // epilogue: every lane holds l(q) in ol[*]; normalize, transpose via LDS
    float inv = 1.0f / ol[0];
    __syncthreads();
    float* Om = (float*)(smem + 8192);        // [64][68] floats (17408 B)
#pragma unroll
    for (int mt = 0; mt < 4; mt++) {
        f32x4 ov;
#pragma unroll
        for (int r = 0; r < 4; r++) ov[r] = o[mt][r] * inv;
        *(f32x4*)(&Om[(wv * 16 + l16) * 68 + mt * 16 + quad * 4]) = ov;
    }
    __syncthreads();
    float* og = out + (long)(b * 2048 + qt * 64 + srow) * 64 + scb;
#pragma unroll
    for (int j = 0; j < 4; j++)
        *(float4*)(og + j * 4) = *(float4*)(&Om[srow * 68 + scb + j * 4]);
}

// ---------------------------------------------------------------------------
extern "C" void kernel_launch(void* const* d_in, const int* in_sizes, int n_in,
                              void* d_out, int out_size, void* d_ws, size_t ws_size,
                              hipStream_t stream) {
    const float* x  = (const float*)d_in[0];
    const float* Wq = (const float*)d_in[1];
    const float* Wk = (const float*)d_in[2];
    const float* Wv = (const float*)d_in[3];
    float* out = (float*)d_out;

    bf16* Qb  = (bf16*)d_ws;           // 32768*64
    bf16* Kb  = Qb + 2097152;
    bf16* Vtg = Kb + 2097152;          // [16][64][2048]
    bf16* Wt  = Vtg + 2097152;         // 6*192*64

    pack_w<<<288, 256, 0, stream>>>(Wq, Wk, Wv, Wt);
    qkv_proj<<<512, 256, 0, stream>>>(x, Wt, Qb, Kb, Vtg);
    flash_attn<<<512, 256, 0, stream>>>(Qb, Kb, Vtg, out);
}